// Round 17
// baseline (130797.949 us; speedup 1.0000x reference)
//
#include <hip/hip_runtime.h>
#include <hip/hip_fp16.h>
#include <math.h>

#define TENC 400
#define TMEL 800
#define NMEL 80
#define ENCD 768
#define PRE  256
#define ARNN 1024
#define DRNN 1024
#define ATTD 128
#define NBLK 256
#define SLOT 32   // 128B-padded flag slots

typedef unsigned uint32;

__device__ __forceinline__ float4 ld4(const float* p){ return *(const float4*)p; }
__device__ __forceinline__ float sigmf(float x){ return 1.f/(1.f + __expf(-x)); }

// ---- agent-scope (L1-bypass, local-L2-hit) state accessors ----
__device__ __forceinline__ float ld_c(const float* p){
  union { unsigned u; float f; } c;
  c.u = __hip_atomic_load((const unsigned*)p, __ATOMIC_RELAXED, __HIP_MEMORY_SCOPE_AGENT);
  return c.f;
}
__device__ __forceinline__ void st_c(float* p, float v){
  union { unsigned u; float f; } c; c.f = v;
  __hip_atomic_store((unsigned*)p, c.u, __ATOMIC_RELAXED, __HIP_MEMORY_SCOPE_AGENT);
}
__device__ __forceinline__ void st2_c(float* p, float a, float b){
  union { unsigned long long u; float f[2]; } c; c.f[0]=a; c.f[1]=b;
  __hip_atomic_store((unsigned long long*)p, c.u, __ATOMIC_RELAXED,
                     __HIP_MEMORY_SCOPE_AGENT);
}
__device__ __forceinline__ uint32 ald(const uint32* p){
  return __hip_atomic_load(p, __ATOMIC_RELAXED, __HIP_MEMORY_SCOPE_AGENT);
}
__device__ __forceinline__ void ast(uint32* p, uint32 v){
  __hip_atomic_store(p, v, __ATOMIC_RELAXED, __HIP_MEMORY_SCOPE_AGENT);
}

// =================== XCD-local barrier (32 blocks, no fences) ===================
__device__ __forceinline__ void xbar(uint32* arr, uint32* relx, uint32 ph,
                                     int xcc, int role)
{
  __syncthreads();
  int tid = threadIdx.x;
  if (tid == 0) {
    asm volatile("s_waitcnt vmcnt(0)" ::: "memory");
    ast(arr + (xcc*32 + role)*SLOT, ph);
  }
  __syncthreads();
  if (role == 0) {
    if (tid < 32) {
      while (ald(arr + (xcc*32 + tid)*SLOT) < ph) __builtin_amdgcn_s_sleep(1);
    }
    __syncthreads();
    if (tid == 0) ast(relx + xcc*SLOT, ph);
  } else if (tid == 0) {
    while (ald(relx + xcc*SLOT) < ph) __builtin_amdgcn_s_sleep(1);
  }
  __syncthreads();
}

// =================== batch-group barrier (8 blocks) ===================
__device__ __forceinline__ void gbar8(uint32* arr, uint32* relg, uint32 ph,
                                      int xcc, int role)
{
  __syncthreads();
  int tid = threadIdx.x;
  int bl = role >> 3;
  if (tid == 0) {
    asm volatile("s_waitcnt vmcnt(0)" ::: "memory");
    ast(arr + (xcc*32 + role)*SLOT, ph);
  }
  __syncthreads();
  if ((role & 7) == 0) {
    if (tid < 8) {
      while (ald(arr + (xcc*32 + bl*8 + tid)*SLOT) < ph) __builtin_amdgcn_s_sleep(1);
    }
    __syncthreads();
    if (tid == 0) ast(relg + (xcc*4 + bl)*SLOT, ph);
  } else if (tid == 0) {
    while (ald(relg + (xcc*4 + bl)*SLOT) < ph) __builtin_amdgcn_s_sleep(1);
  }
  __syncthreads();
}

// =================== prenet: xsT[t][k=256][b=32] ===================
__global__ __launch_bounds__(256) void prenet_kernel(
    const float* __restrict__ din, const float* __restrict__ w1,
    const float* __restrict__ w2, float* __restrict__ xsT)
{
  int t = blockIdx.x;
  __shared__ float f_s[32*80];
  __shared__ float p_s[32*257];
  for (int id = threadIdx.x; id < 32*80; id += 256) {
    int b = id / 80, m = id - b*80;
    f_s[id] = (t == 0) ? 0.f : din[b*(NMEL*TMEL) + m*TMEL + (t-1)];
  }
  __syncthreads();
  for (int b = 0; b < 32; ++b) {
    int k = threadIdx.x;
    float acc = 0.f;
    #pragma unroll 4
    for (int m = 0; m < 80; ++m) acc += f_s[b*80+m] * w1[k*80+m];
    p_s[b*257+k] = fmaxf(acc, 0.f);
  }
  __syncthreads();
  int b = threadIdx.x & 31, jslot = threadIdx.x >> 5;
  for (int jj = 0; jj < 32; ++jj) {
    int j = jslot*32 + jj;
    const float* w2r = w2 + j*256;
    float acc = 0.f;
    #pragma unroll 4
    for (int kk = 0; kk < 256; ++kk) acc += p_s[b*257+kk] * w2r[kk];
    xsT[(size_t)t*8192 + j*32 + b] = fmaxf(acc, 0.f);
  }
}

// =================== pmem16[b][t][128] (fp16) ===================
__global__ __launch_bounds__(256) void pmem_kernel(
  const float* __restrict__ mem, const float* __restrict__ mw, __half* __restrict__ pm16)
{
  int b = blockIdx.y, tc = blockIdx.x;
  int a = threadIdx.x & 127, th = threadIdx.x >> 7;
  for (int i = 0; i < 8; ++i) {
    int tt = tc*16 + th + 2*i;
    const float* mrow = mem + (size_t)b*(TENC*ENCD) + (size_t)tt*ENCD;
    const float* wrow = mw + a*ENCD;
    float acc = 0.f;
    #pragma unroll 4
    for (int e4 = 0; e4 < ENCD; e4 += 4) {
      float4 mv = ld4(mrow+e4), wv = ld4(wrow+e4);
      acc += mv.x*wv.x + mv.y*wv.y + mv.z*wv.z + mv.w*wv.w;
    }
    pm16[b*(TENC*ATTD) + tt*ATTD + a] = __float2half(acc);
  }
}

// =================== mem16[b][jc][tt*48+jp] (fp16 pairs) ===================
__global__ __launch_bounds__(256) void mem16_kernel(
  const float* __restrict__ mem, __half2* __restrict__ m16)
{
  int b = blockIdx.y, jc = blockIdx.x;
  const float* mb = mem + (size_t)b*(TENC*ENCD) + jc*96;
  __half2* dst = m16 + ((size_t)(b*8 + jc))*19200;
  for (int idx = threadIdx.x; idx < 19200; idx += 256) {
    int tt = idx / 48, jp = idx - tt*48;
    dst[idx] = __floats2half2_rn(mb[(size_t)tt*ENCD + jp*2],
                                 mb[(size_t)tt*ENCD + jp*2 + 1]);
  }
}

// =================== fp32 -> fp16 convert ===================
__global__ __launch_bounds__(256) void cvt16_kernel(
  const float* __restrict__ src, __half* __restrict__ dst, int n)
{
  int i = blockIdx.x*256 + threadIdx.x;
  int st = gridDim.x*256;
  for (; i < n; i += st) dst[i] = __float2half(src[i]);
}

// =================== args ===================
struct DecArgs {
  const float *xsT;
  const __half *awih16, *awhh16, *dwih16, *dwhh16, *qw16, *pm16;
  const __half2 *mem16;
  const float *abih, *abhh, *dbih, *dbhh;
  const float *cw, *ldw, *vw;
  const int*  mlen;
  const float *pw, *pb, *gw, *gb;
  float *ahX, *dhX, *ctxX, *awX, *awcX, *eX;
  float *out_mel, *out_gate, *out_align;
  uint32 *roleCtr, *arr, *relx, *relg;
};

// =================== unified DMA GEMM (W + X in one ordered stream) ===================
// Slot (10 KB): W [u(32)][128h] at +0 (8 KB), X [k(128)][b(4)] fp32 at +8192 (2 KB).
// Per chunk: 8 W-DMA (aux 0) + 2 X-DMA (aux sc0 -> L1-bypass for mutable state).

#define SBAR() __builtin_amdgcn_sched_barrier(0)
#define WAITV20() { asm volatile("s_waitcnt vmcnt(20)" ::: "memory"); SBAR(); }
#define WAITV10() { asm volatile("s_waitcnt vmcnt(10)" ::: "memory"); SBAR(); }
#define WAITV0()  { asm volatile("s_waitcnt vmcnt(0)"  ::: "memory"); SBAR(); }

template<int KIH>
__device__ __forceinline__ void dmaW(const __half* __restrict__ wih,
                                     const __half* __restrict__ whh,
                                     int g, int u0g, int c, char* slot, int lane)
{
  const int kk = c*128;
  const __half* base = (kk < KIH) ? wih : whh;
  const int kbase = (kk < KIH) ? kk : (kk - KIH);
  const size_t kstr = (kk < KIH) ? (size_t)KIH : (size_t)1024;
  const int r = lane >> 4, kp = lane & 15;
  const __half* src = base + (size_t)(g*1024 + u0g + r)*kstr + kbase + kp*8;
  #pragma unroll
  for (int i = 0; i < 8; ++i) {
    __builtin_amdgcn_global_load_lds(
      (const __attribute__((address_space(1))) void*)(src + (size_t)(i*4)*kstr),
      (__attribute__((address_space(3))) void*)(slot + i*1024), 16, 0, 0);
  }
}

template<int E0, int E1, bool S0W>
__device__ __forceinline__ void dmaX(int c, int lane, int b0,
  const float* __restrict__ s0, const float* __restrict__ s1,
  const float* __restrict__ s2, char* slot)
{
  #pragma unroll
  for (int j = 0; j < 2; ++j) {
    int k = c*128 + j*64 + lane;
    const float* src;
    if (S0W && c < E0)      src = s0 + (size_t)k*32 + b0;
    else if (c < E0)        src = s0 + (size_t)k*4;
    else if (c < E1)        src = s1 + (size_t)(k - E0*128)*4;
    else                    src = s2 + (size_t)(k - E1*128)*4;
    __builtin_amdgcn_global_load_lds(
      (const __attribute__((address_space(1))) void*)src,
      (__attribute__((address_space(3))) void*)(slot + 8192 + j*1024 + lane*16),
      16, 0, 1);   // sc0: bypass L1 (mutable state)
  }
}

__device__ __forceinline__ void compW(const char* slot, int lane, float* acc)
{
  float4 xlo = *(const float4*)(slot + 8192 + lane*32);
  float4 xhi = *(const float4*)(slot + 8192 + lane*32 + 16);
  #pragma unroll
  for (int u = 0; u < 32; ++u) {
    __half2 w2 = *(const __half2*)(slot + u*256 + lane*4);
    float2 wf = __half22float2(w2);
    acc[u*4+0] += wf.x*xlo.x + wf.y*xhi.x;
    acc[u*4+1] += wf.x*xlo.y + wf.y*xhi.y;
    acc[u*4+2] += wf.x*xlo.z + wf.y*xhi.z;
    acc[u*4+3] += wf.x*xlo.w + wf.y*xhi.w;
  }
}

#define RS_ROUND(m, n) { bool hi = (lane & m) != 0; \
  _Pragma("unroll") for (int i = 0; i < n; ++i) { \
    float v = hi ? acc[i] : acc[i+n]; \
    float o = __shfl_xor(v, m); \
    acc[i] = (hi ? acc[i+n] : acc[i]) + o; } }

template<int NC, int E0, int E1, int KIH, bool S0W>
__device__ void gemm_stream(const __half* __restrict__ wih,
                            const __half* __restrict__ whh,
                            int u0g, int b0,
                            const float* __restrict__ s0,
                            const float* __restrict__ s1,
                            const float* __restrict__ s2,
                            char* ringAll, float* G)
{
  const int tid = threadIdx.x;
  const int g = tid >> 6, lane = tid & 63;
  char* ring = ringAll + g*30720;          // 3 slots x 10 KB
  float acc[128];
  #pragma unroll
  for (int i = 0; i < 128; ++i) acc[i] = 0.f;

  dmaW<KIH>(wih, whh, g, u0g, 0, ring, lane);
  dmaX<E0,E1,S0W>(0, lane, b0, s0, s1, s2, ring);
  dmaW<KIH>(wih, whh, g, u0g, 1, ring + 10240, lane);
  dmaX<E0,E1,S0W>(1, lane, b0, s0, s1, s2, ring + 10240);
  SBAR();

  int sc = 0, sp = 2;
  #pragma unroll 1
  for (int c = 0; c < NC; ++c) {
    if (c + 2 < NC) {
      char* ps = ring + sp*10240;
      dmaW<KIH>(wih, whh, g, u0g, c+2, ps, lane);
      dmaX<E0,E1,S0W>(c+2, lane, b0, s0, s1, s2, ps);
      SBAR();
    }
    if (c + 2 < NC)      { WAITV20(); }
    else if (c + 1 < NC) { WAITV10(); }
    else                 { WAITV0();  }
    compW(ring + sc*10240, lane, acc);
    SBAR();
    sc = (sc+1 == 3) ? 0 : sc+1;
    sp = (sp+1 == 3) ? 0 : sp+1;
  }

  RS_ROUND(32,64) RS_ROUND(16,32) RS_ROUND(8,16)
  RS_ROUND(4,8)   RS_ROUND(2,4)   RS_ROUND(1,2)
  {
    int pidx = lane*2;
    int u = pidx >> 2, b = pidx & 3;
    *(float2*)(G + g*128 + u*4 + b) = make_float2(acc[0], acc[1]);
  }
}

// =================== LSTM cell (c in registers) ===================
__device__ __forceinline__ void cell_x(const float* G, int u0g,
  const float* __restrict__ bih, const float* __restrict__ bhh,
  float& creg, float* hbuf, float* __restrict__ hXw)
{
  int tid = threadIdx.x;
  __syncthreads();
  if (tid < 128) {
    int u = tid >> 2, b = tid & 3;
    int uu = u0g + u;
    float gi = G[0*128 + u*4+b] + bih[uu]        + bhh[uu];
    float gf = G[1*128 + u*4+b] + bih[1024+uu]   + bhh[1024+uu];
    float gg = G[2*128 + u*4+b] + bih[2048+uu]   + bhh[2048+uu];
    float go = G[3*128 + u*4+b] + bih[3072+uu]   + bhh[3072+uu];
    float cn = sigmf(gf)*creg + sigmf(gi)*tanhf(gg);
    creg = cn;
    hbuf[tid] = sigmf(go)*tanhf(cn);
  }
  __syncthreads();
  if (tid < 32) {
    float4 hv = *(float4*)(hbuf + tid*4);
    st2_c(hXw + (size_t)(u0g + tid)*4,     hv.x, hv.y);
    st2_c(hXw + (size_t)(u0g + tid)*4 + 2, hv.z, hv.w);
  }
  __syncthreads();
}

// =================== projection (XCD rows 0..323) ===================
__device__ void proj_x(int role, int xcc, int t,
  const float* __restrict__ dhR, const float* __restrict__ ctxX, const DecArgs& p)
{
  int tid = threadIdx.x;
  int w = tid >> 6, lane = tid & 63;
  int base = role*10 + (role < 4 ? role : 4);
  int cnt  = (role < 4) ? 11 : 10;
  for (int i = w; i < cnt; i += 4) {
    int d = base + i;
    int bl = d / 81, r = d - bl*81;
    const float* wr = (r < 80) ? (p.pw + (size_t)r*1792) : p.gw;
    float a = 0.f;
    #pragma unroll 4
    for (int ii = 0; ii < 28; ++ii) {
      int k = lane + ii*64;
      float x = (k < 1024) ? ld_c(dhR + (size_t)k*4 + bl)
                           : ld_c(ctxX + (size_t)(k-1024)*4 + bl);
      a += x * wr[k];
    }
    #pragma unroll
    for (int m = 32; m >= 1; m >>= 1) a += __shfl_xor(a, m);
    if (lane == 0) {
      int b = xcc*4 + bl;
      if (r < 80) p.out_mel[((size_t)b*80 + r)*TMEL + t] = a + p.pb[r];
      else        p.out_gate[(size_t)b*TMEL + t]         = a + p.gb[0];
    }
  }
}

// =================== P2: energies (+pq) for (bl, c8) ===================
__device__ void energies_x(int bl, int c8, int xcc, const DecArgs& p,
  const float* __restrict__ ahW, const float* __restrict__ awXl,
  const float* __restrict__ awcXl, float* __restrict__ eXl, float* scr)
{
  int t0 = c8*50;
  float* ah_s  = scr;           // 1024
  float* pq_s  = scr + 1024;    // 128
  float* part  = scr + 1152;    // 256
  float* aw_s  = scr + 1408;    // 80
  float* awc_s = scr + 1488;    // 80
  float* loc_s = scr + 1568;    // 50*33
  float* epart = scr + 3218;    // 200
  int tid = threadIdx.x;
  #pragma unroll
  for (int i = 0; i < 4; ++i) {
    int u = tid + i*256;
    ah_s[u] = ld_c(ahW + (size_t)u*4 + bl);
  }
  if (tid >= 96) {              // 160 threads -> halo i in [0,160)
    int i = tid - 96;
    int h = (i < 80) ? i : i - 80;
    bool isC = i >= 80;
    int gidx = t0 - 15 + h;
    float v = (gidx >= 0 && gidx < TENC)
            ? (isC ? ld_c(awcXl + gidx) : ld_c(awXl + gidx)) : 0.f;
    if (isC) awc_s[h] = v; else aw_s[h] = v;
  }
  __syncthreads();
  {
    int a = tid & 127, kh = tid >> 7;
    const __half* qr = p.qw16 + (size_t)a*1024 + kh*512;
    const float*  ar = ah_s + kh*512;
    float acc = 0.f;
    for (int k = 0; k < 512; k += 8) {
      uint4 hv = *(const uint4*)(qr + k);
      const __half2* h2 = (const __half2*)&hv;
      #pragma unroll
      for (int q = 0; q < 4; ++q) {
        float2 wf = __half22float2(h2[q]);
        acc += ar[k+q*2]*wf.x + ar[k+q*2+1]*wf.y;
      }
    }
    part[tid] = acc;
  }
  __syncthreads();
  if (tid < 128) pq_s[tid] = part[tid] + part[tid+128];
  for (int id = tid; id < 50*32; id += 256) {
    int tl = id >> 5, f = id & 31;
    const float* w0 = p.cw + f*62;
    float acc = 0.f;
    #pragma unroll
    for (int k = 0; k < 31; ++k)
      acc += aw_s[tl+k]*w0[k] + awc_s[tl+k]*w0[31+k];
    loc_s[tl*33 + f] = acc;
  }
  __syncthreads();
  if (tid < 200) {
    int tl = tid >> 2, qa = tid & 3;
    int tt = t0 + tl;
    const __half* pm = p.pm16 + (size_t)(xcc*4+bl)*(TENC*ATTD) + (size_t)tt*ATTD;
    float s = 0.f;
    for (int a = qa*32; a < qa*32 + 32; ++a) {
      const float* lw = p.ldw + a*32;
      float pl = 0.f;
      #pragma unroll 8
      for (int f = 0; f < 32; ++f) pl += loc_s[tl*33 + f] * lw[f];
      s += p.vw[a] * tanhf(pq_s[a] + __half2float(pm[a]) + pl);
    }
    epart[tl*4 + qa] = s;
  }
  __syncthreads();
  if (tid < 50) {
    int tt = t0 + tid;
    float v = epart[tid*4] + epart[tid*4+1] + epart[tid*4+2] + epart[tid*4+3];
    if (tt >= p.mlen[xcc*4+bl]) v = -1000000000.0f;
    st_c(eXl + tt, v);
  }
}

// =================== P3: softmax + ctx for (bl, jc) ===================
__device__ void smctx_x(int bl, int jc, int xcc, int t, const DecArgs& p,
  const float* __restrict__ eXl, float* __restrict__ awXl, float* __restrict__ awcXl,
  float* __restrict__ ctxX, const __half2* __restrict__ mslice, float* scr)
{
  float* red   = scr;          // 256
  float* aw_s  = scr + 256;    // 400
  float* cpart = scr + 656;    // 384
  int tid = threadIdx.x;
  float v0 = ld_c(eXl + tid);
  float v1 = (tid + 256 < TENC) ? ld_c(eXl + tid + 256) : -3.0e38f;
  red[tid] = fmaxf(v0, v1); __syncthreads();
  for (int s = 128; s > 0; s >>= 1) {
    if (tid < s) red[tid] = fmaxf(red[tid], red[tid+s]);
    __syncthreads();
  }
  float mx = red[0]; __syncthreads();
  float p0 = __expf(v0 - mx);
  float p1 = (tid + 256 < TENC) ? __expf(v1 - mx) : 0.f;
  red[tid] = p0 + p1; __syncthreads();
  for (int s = 128; s > 0; s >>= 1) {
    if (tid < s) red[tid] += red[tid+s];
    __syncthreads();
  }
  float inv = 1.f / red[0];
  aw_s[tid] = p0 * inv;
  if (tid + 256 < TENC) aw_s[tid + 256] = p1 * inv;
  __syncthreads();
  if (tid < 192) {
    int jp = tid % 48, h = tid / 48;
    float ax = 0.f, ay = 0.f;
    for (int tt = h*100; tt < h*100 + 100; ++tt) {
      float av = aw_s[tt];
      float2 m = __half22float2(mslice[tt*48 + jp]);
      ax += av * m.x; ay += av * m.y;
    }
    cpart[(h*48 + jp)*2]     = ax;
    cpart[(h*48 + jp)*2 + 1] = ay;
  }
  __syncthreads();
  if (tid < 48) {
    float sx = cpart[tid*2]        + cpart[(48+tid)*2]
             + cpart[(96+tid)*2]   + cpart[(144+tid)*2];
    float sy = cpart[tid*2+1]      + cpart[(48+tid)*2+1]
             + cpart[(96+tid)*2+1] + cpart[(144+tid)*2+1];
    int j = jc*96 + tid*2;
    st_c(ctxX + (size_t)j*4 + bl, sx);
    st_c(ctxX + (size_t)(j+1)*4 + bl, sy);
  }
  if (jc == 0) {
    for (int i = tid; i < TENC; i += 256) {
      float a = aw_s[i];
      st_c(awXl + i, a);
      st_c(awcXl + i, ld_c(awcXl + i) + a);
      p.out_align[((size_t)(xcc*4+bl)*TMEL + t)*TENC + i] = a;
    }
  }
}

// =================== THE persistent XCD-partitioned kernel ===================
__global__ __launch_bounds__(256, 1) void decoder_loop(DecArgs p)
{
  __shared__ __align__(16) char Wring[122880];  // 4 waves x 3 slots x 10 KB
  __shared__ float G[512];
  __shared__ float hbuf[128];
  __shared__ int s_xcc, s_role;
  int tid = threadIdx.x;
  float* scr = (float*)Wring;                    // phase scratch (union w/ ring)

  if (tid == 0) {
    uint32 x;
    asm volatile("s_getreg_b32 %0, hwreg(HW_REG_XCC_ID)" : "=s"(x));
    int xc = (int)(x & 7);
    s_xcc = xc;
    s_role = (int)atomicAdd(&p.roleCtr[xc], 1u);
  }
  __syncthreads();
  const int xcc = s_xcc, role = s_role & 31;
  const int u0g = role*32;
  const int bl = role >> 3, jc = role & 7;
  const int b0 = xcc*4;

  float* ctxX  = p.ctxX + (size_t)xcc*3072;
  float* awXl  = p.awX  + (size_t)xcc*1600 + bl*400;
  float* awcXl = p.awcX + (size_t)xcc*1600 + bl*400;
  float* eXl   = p.eX   + (size_t)xcc*1600 + bl*400;
  const __half2* mslice = p.mem16 + ((size_t)((xcc*4+bl)*8 + jc))*19200;

  float cA = 0.f, cD = 0.f;
  uint32 ph = 0;

  for (int t = 0; t < TMEL; ++t) {
    const float* ahR = p.ahX + (size_t)((t+1)&1)*32768 + (size_t)xcc*4096;
    float*       ahW = p.ahX + (size_t)(t&1)*32768     + (size_t)xcc*4096;
    const float* dhR = p.dhX + (size_t)((t+1)&1)*32768 + (size_t)xcc*4096;
    float*       dhW = p.dhX + (size_t)(t&1)*32768     + (size_t)xcc*4096;

    // ---- P1: proj(t-1) + att-GEMM + cell ----
    if (t > 0) proj_x(role, xcc, t-1, dhR, ctxX, p);
    gemm_stream<16, 2, 8, 1024, true>(p.awih16, p.awhh16, u0g, b0,
        p.xsT + (size_t)t*8192, ctxX, ahR, Wring, G);
    cell_x(G, u0g, p.abih, p.abhh, cA, hbuf, ahW);
    xbar(p.arr, p.relx, ++ph, xcc, role);

    // ---- P2: energies (+pq) ----
    energies_x(bl, jc, xcc, p, ahW, awXl, awcXl, eXl, scr);
    gbar8(p.arr, p.relg, ++ph, xcc, role);

    // ---- P3: softmax + ctx ----
    smctx_x(bl, jc, xcc, t, p, eXl, awXl, awcXl, ctxX, mslice, scr);
    xbar(p.arr, p.relx, ++ph, xcc, role);

    // ---- P4: dec-GEMM + cell ----
    gemm_stream<22, 8, 14, 1792, false>(p.dwih16, p.dwhh16, u0g, 0,
        ahW, ctxX, dhR, Wring, G);
    cell_x(G, u0g, p.dbih, p.dbhh, cD, hbuf, dhW);
    xbar(p.arr, p.relx, ++ph, xcc, role);
  }

  // final projection (t = TMEL-1)
  proj_x(role, xcc, TMEL-1,
         p.dhX + (size_t)((TMEL-1)&1)*32768 + (size_t)xcc*4096, ctxX, p);
}

extern "C" void kernel_launch(void* const* d_in, const int* in_sizes, int n_in,
                              void* d_out, int out_size, void* d_ws, size_t ws_size,
                              hipStream_t stream)
{
  const float* memory = (const float*)d_in[0];
  const float* din    = (const float*)d_in[1];
  const float* w1     = (const float*)d_in[3];
  const float* w2     = (const float*)d_in[4];
  const float* awih   = (const float*)d_in[5];
  const float* awhh   = (const float*)d_in[6];
  const float* abih   = (const float*)d_in[7];
  const float* abhh   = (const float*)d_in[8];
  const float* q_w    = (const float*)d_in[9];
  const float* mem_w  = (const float*)d_in[10];
  const float* v_w    = (const float*)d_in[11];
  const float* cw     = (const float*)d_in[12];
  const float* ldw    = (const float*)d_in[13];
  const float* dwih   = (const float*)d_in[14];
  const float* dwhh   = (const float*)d_in[15];
  const float* dbih   = (const float*)d_in[16];
  const float* dbhh   = (const float*)d_in[17];
  const float* pw     = (const float*)d_in[18];
  const float* pb     = (const float*)d_in[19];
  const float* gw     = (const float*)d_in[20];
  const float* gb     = (const float*)d_in[21];
  const int*   mlen   = (const int*)d_in[22];

  float* p = (float*)d_ws;
  float* xsT    = p;              p += 800*256*32;
  __half* awih16 = (__half*)p;    p += 2097152;
  __half* awhh16 = (__half*)p;    p += 2097152;
  __half* dwih16 = (__half*)p;    p += 3670016;
  __half* dwhh16 = (__half*)p;    p += 2097152;
  __half* qw16   = (__half*)p;    p += 65536;
  __half* pm16   = (__half*)p;    p += 819200;
  __half2* mem16 = (__half2*)p;   p += 4915200;
  // ---- zeroed block ----
  float* zs      = p;
  uint32* roleCtr = (uint32*)p;   p += 8;
  uint32* arr    = (uint32*)p;    p += 256*SLOT;
  uint32* relx   = (uint32*)p;    p += 8*SLOT;
  uint32* relg   = (uint32*)p;    p += 32*SLOT;
  float* ahX     = p;             p += 2*8*1024*4;
  float* dhX     = p;             p += 2*8*1024*4;
  float* ctxX    = p;             p += 8*768*4;
  float* awX     = p;             p += 8*4*400;
  float* awcX    = p;             p += 8*4*400;
  float* eX      = p;             p += 8*4*400;
  size_t zcount  = (size_t)(p - zs);
  // ---- end zeroed block ----

  float* out_mel   = (float*)d_out;
  float* out_gate  = out_mel + 32*80*800;
  float* out_align = out_gate + 32*800;

  hipMemsetAsync(zs, 0, zcount*sizeof(float), stream);
  prenet_kernel<<<TMEL, 256, 0, stream>>>(din, w1, w2, xsT);
  pmem_kernel<<<dim3(25,32), 256, 0, stream>>>(memory, mem_w, pm16);
  mem16_kernel<<<dim3(8,32), 256, 0, stream>>>(memory, mem16);
  cvt16_kernel<<<256, 256, 0, stream>>>(q_w, qw16, 128*1024);
  cvt16_kernel<<<2048, 256, 0, stream>>>(awih, awih16, 4096*1024);
  cvt16_kernel<<<2048, 256, 0, stream>>>(awhh, awhh16, 4096*1024);
  cvt16_kernel<<<2048, 256, 0, stream>>>(dwih, dwih16, 4096*1792);
  cvt16_kernel<<<2048, 256, 0, stream>>>(dwhh, dwhh16, 4096*1024);

  DecArgs a;
  a.xsT = xsT;
  a.awih16 = awih16; a.awhh16 = awhh16; a.dwih16 = dwih16; a.dwhh16 = dwhh16;
  a.qw16 = qw16; a.pm16 = pm16; a.mem16 = mem16;
  a.abih = abih; a.abhh = abhh; a.dbih = dbih; a.dbhh = dbhh;
  a.cw = cw; a.ldw = ldw; a.vw = v_w; a.mlen = mlen;
  a.pw = pw; a.pb = pb; a.gw = gw; a.gb = gb;
  a.ahX = ahX; a.dhX = dhX; a.ctxX = ctxX; a.awX = awX; a.awcX = awcX; a.eX = eX;
  a.out_mel = out_mel; a.out_gate = out_gate; a.out_align = out_align;
  a.roleCtr = roleCtr; a.arr = arr; a.relx = relx; a.relg = relg;

  decoder_loop<<<NBLK, 256, 0, stream>>>(a);
}